// Round 11
// baseline (299.745 us; speedup 1.0000x reference)
//
#include <hip/hip_runtime.h>
#include <math.h>

#define RQ 6               // per-lane queue depth (fallback path only)
constexpr int WRANKS = 768; // phase-1 rank window (12 chunks of 64)
constexpr int WCH = 12;

typedef __attribute__((ext_vector_type(8))) short s8v;    // 8 bf16 (4 VGPRs)
typedef __attribute__((ext_vector_type(4))) float f32x4;  // MFMA acc

__device__ inline unsigned short f2bf(float x) {          // RNE f32->bf16
    const unsigned int u = __float_as_uint(x);
    return (unsigned short)((u + 0x7FFFu + ((u >> 16) & 1u)) >> 16);
}

// N(0,1) quantiles at i/64, i=1..63. PERF-ONLY hint; CSR uses exact counts.
__constant__ float ZB[63] = {
    -2.1539f, -1.8627f, -1.6759f, -1.5341f, -1.4178f, -1.3180f, -1.2299f, -1.1503f,
    -1.0775f, -1.0100f, -0.9468f, -0.8871f, -0.8305f, -0.7764f, -0.7245f, -0.6745f,
    -0.6261f, -0.5791f, -0.5334f, -0.4888f, -0.4451f, -0.4023f, -0.3601f, -0.3186f,
    -0.2776f, -0.2372f, -0.1971f, -0.1573f, -0.1178f, -0.0784f, -0.0392f,  0.0000f,
     0.0392f,  0.0784f,  0.1178f,  0.1573f,  0.1971f,  0.2372f,  0.2776f,  0.3186f,
     0.3601f,  0.4023f,  0.4451f,  0.4888f,  0.5334f,  0.5791f,  0.6261f,  0.6745f,
     0.7245f,  0.7764f,  0.8305f,  0.8871f,  0.9468f,  1.0100f,  1.0775f,  1.1503f,
     1.2299f,  1.3180f,  1.4178f,  1.5341f,  1.6759f,  1.8627f,  2.1539f };

// ---------------------------------------------------------------------------
// K0 (fused prep): blocks 0..B*2-1   : z-bin CSR build (one block per list)
//                  blocks B*2..+31   : query gather (1024 queries/block)
//                  last block        : zero stats1/stats2
// ---------------------------------------------------------------------------
__global__ __launch_bounds__(1024) void prep_kernel(
    const float* __restrict__ p0, const float* __restrict__ p1,
    const float* __restrict__ wt, const int* __restrict__ perm,
    float4* __restrict__ sp, int* __restrict__ starts,
    float4* __restrict__ newp, float* __restrict__ statsz,
    int N, int B)
{
    const int t = threadIdx.x;
    const int nzb = B * 2;
    if ((int)blockIdx.x < nzb) {
        // ---- zbin branch (identical math to the verified zbin_kernel) ----
        __shared__ int cnt[64], off[64], cur[64];
        const int bl = blockIdx.x;                // b*2 + list
        const int b = bl >> 1, list = bl & 1;
        const float* rb = (list ? p1 : p0) + (size_t)(b * 3) * N;
        if (t < 64) { cnt[t] = 0; cur[t] = 0; }
        __syncthreads();
        int mybin[4]; float mx[4], my[4], mz[4];
        for (int i = 0; i < 4; ++i) {
            const int idx = i * 1024 + t;
            const float z = rb[2 * N + idx];
            mx[i] = rb[idx]; my[i] = rb[N + idx]; mz[i] = z;
            int bin = 0;
#pragma unroll
            for (int s = 32; s; s >>= 1)
                if (bin + s <= 63 && z >= ZB[bin + s - 1]) bin += s;
            mybin[i] = bin;
            atomicAdd(&cnt[bin], 1);
        }
        __syncthreads();
        if (t < 64) {                             // wave 0: exclusive prefix
            const int v = cnt[t];
            int x = v;
#pragma unroll
            for (int o = 1; o < 64; o <<= 1) {
                const int y = __shfl_up(x, o);
                if (t >= o) x += y;
            }
            off[t] = x - v;
            starts[bl * 65 + t] = x - v;
            if (t == 63) starts[bl * 65 + 64] = x;
        }
        __syncthreads();
        for (int i = 0; i < 4; ++i) {
            const int bin = mybin[i];
            const int pos = off[bin] + atomicAdd(&cur[bin], 1);
            sp[(size_t)bl * 4096 + pos] =
                make_float4(mx[i], my[i], mz[i],
                            fmaf(mx[i], mx[i], fmaf(my[i], my[i], mz[i] * mz[i])));
        }
    } else if ((int)blockIdx.x < nzb + (B * N) / 1024) {
        // ---- gather branch ----
        const int q = ((int)blockIdx.x - nzb) * 1024 + t;
        const int b = q / N, n = q - b * N;
        const float wt0 = wt[b * 2];
        const int N0 = (int)(N * wt0);
        int j; const float* src;
        if (n < N0) { j = perm[(b * 2) * N + n];            src = p0; }
        else        { j = perm[(b * 2 + 1) * N + (n - N0)]; src = p1; }
        newp[q] = make_float4(src[(b * 3) * N + j], src[(b * 3 + 1) * N + j],
                              src[(b * 3 + 2) * N + j], 0.f);
    } else {
        // ---- stats zero branch ----
        if (t < B * 30) statsz[t] = 0.f;
    }
}

// ---------------------------------------------------------------------------
// K1 helpers
// ---------------------------------------------------------------------------
__device__ __forceinline__ void cpush(unsigned key, unsigned pos, unsigned Tu,
                                      bool valid, uint2* __restrict__ cc,
                                      int& cnt)
{
    const bool pred = valid && (key <= Tu);
    const unsigned long long bal = __ballot(pred);
    const unsigned below = __builtin_amdgcn_mbcnt_hi(
        (unsigned)(bal >> 32), __builtin_amdgcn_mbcnt_lo((unsigned)bal, 0u));
    const unsigned idx = (unsigned)cnt + below;
    if (pred && idx < 64u) cc[idx] = make_uint2(key, pos);
    cnt += (int)__popcll(bal);
}

__device__ __forceinline__ void cscan(const float4* __restrict__ L,
                                      int bs, int be,
                                      float qx, float qy, float qz, float qq,
                                      unsigned Tu, uint2* __restrict__ cc,
                                      int& cnt, int lane)
{
    for (int p = bs; p < be; p += 64) {
        const int pos = p + lane;
        const float4 pc = L[min(pos, be - 1)];
        const float dt = fmaf(qz, pc.z, fmaf(qy, pc.y, qx * pc.x));
        const float d = fmaxf(fmaf(-2.f, dt, pc.w + qq), 0.f);
        cpush(__float_as_uint(d), (unsigned)pos, Tu, pos < be, cc, cnt);
    }
}

// single-list 64-wide bitonic sort of candidates, write top-kk.
__device__ __forceinline__ void sort_write(
    const uint2* __restrict__ cc, int cnt,
    const float4* __restrict__ L, int kk, int obase,
    float qx, float qy, float qz, float4* __restrict__ feat, int lane)
{
    const uint2 v = cc[lane];
    unsigned vk = (lane < cnt) ? v.x : 0xFFFFFFFFu;
    unsigned vp = (lane < cnt) ? v.y : 0xFFFFFFFFu;
#pragma unroll
    for (int k2 = 2; k2 <= 64; k2 <<= 1) {
#pragma unroll
        for (int jj = k2 >> 1; jj; jj >>= 1) {
            const unsigned yk = __shfl_xor(vk, jj);
            const unsigned yp = __shfl_xor(vp, jj);
            const bool keepmin = (((lane & jj) == 0) == ((lane & k2) == 0));
            const bool lt = (vk < yk) || ((vk == yk) && (vp < yp));
            const bool sely = keepmin ? (!lt) : lt;
            vk = sely ? yk : vk;
            vp = sely ? yp : vp;
        }
    }
    if (lane < kk) {
        const float4 pc = L[vp & 4095u];
        const float rx = pc.x - qx, ry = pc.y - qy, rz = pc.z - qz;
        feat[obase + lane] =
            make_float4(rx, ry, rz, sqrtf(fmaf(rx, rx, fmaf(ry, ry, rz * rz))));
    }
}

// ---- fallback path (cnt>64, astronomically rare): full-list queue scan ----
__device__ __forceinline__ void qpush(unsigned (&kh)[RQ], unsigned (&kl)[RQ],
                                      unsigned key, unsigned pos)
{
    bool cb[RQ];
#pragma unroll
    for (int s = 0; s < RQ; ++s) cb[s] = key < kh[s];
#pragma unroll
    for (int s = RQ - 1; s >= 1; --s) {
        kh[s] = cb[s - 1] ? kh[s - 1] : (cb[s] ? key : kh[s]);
        kl[s] = cb[s - 1] ? kl[s - 1] : (cb[s] ? pos : kl[s]);
    }
    kh[0] = cb[0] ? key : kh[0];
    kl[0] = cb[0] ? pos : kl[0];
}

__device__ __forceinline__ void pop_extract(
    unsigned (&kh)[RQ], unsigned (&kl)[RQ], int kk,
    const float4* __restrict__ L, int obase,
    float qx, float qy, float qz, float4* __restrict__ feat, int lane)
{
    unsigned mwin = 0;
    for (int rr = 0; rr < kk; ++rr) {
        unsigned gg = kh[0];
#pragma unroll
        for (int off = 32; off; off >>= 1) gg = min(gg, __shfl_xor(gg, off));
        const bool tied = (kh[0] == gg);
        unsigned mc;
        const unsigned long long bal = __ballot(tied);
        if (bal & (bal - 1)) {
            mc = tied ? kl[0] : 0xFFFFFFFFu;
#pragma unroll
            for (int off = 32; off; off >>= 1) mc = min(mc, __shfl_xor(mc, off));
        } else {
            mc = __shfl(kl[0], (int)__ffsll((long long)bal) - 1);
        }
        const bool w = tied && (kl[0] == mc);
        if (lane == rr) mwin = mc;
#pragma unroll
        for (int s = 0; s < RQ - 1; ++s) {
            kh[s] = w ? kh[s + 1] : kh[s];
            kl[s] = w ? kl[s + 1] : kl[s];
        }
        kh[RQ - 1] = w ? 0xFFFFFFFFu : kh[RQ - 1];
        kl[RQ - 1] = w ? 0xFFFFFFFFu : kl[RQ - 1];
    }
    if (lane < kk) {
        const float4 pc = L[mwin & 4095u];
        const float rx = pc.x - qx, ry = pc.y - qy, rz = pc.z - qz;
        feat[obase + lane] =
            make_float4(rx, ry, rz, sqrtf(fmaf(rx, rx, fmaf(ry, ry, rz * rz))));
    }
}

__device__ __forceinline__ void fallback_full(
    const float4* __restrict__ L, int Npts, int kk, int obase,
    float qx, float qy, float qz, float qq,
    float4* __restrict__ feat, int lane)
{
    unsigned kh[RQ], kl[RQ];
#pragma unroll
    for (int s = 0; s < RQ; ++s) { kh[s] = 0xFFFFFFFFu; kl[s] = 0xFFFFFFFFu; }
    for (int p = 0; p < Npts; p += 64) {
        const int pos = p + lane;
        const float4 pc = L[min(pos, Npts - 1)];
        const float dt = fmaf(qz, pc.z, fmaf(qy, pc.y, qx * pc.x));
        const float d = fmaxf(fmaf(-2.f, dt, pc.w + qq), 0.f);
        const unsigned key = (pos < Npts) ? __float_as_uint(d) : 0xFFFFFFFFu;
        qpush(kh, kl, key, (unsigned)pos);
    }
    pop_extract(kh, kl, kk, L, obase, qx, qy, qz, feat, lane);
}

// ---------------------------------------------------------------------------
// K1: exact kNN. R11 = R9 exactly (1-wave blocks, LINEAR task mapping,
// batched-ballot compaction). The R10 XCD swizzle is REVERTED: it cut
// FETCH 6.2->1.1 MB (L2 win) but cost +4us (measured) by destroying L1
// locality between co-resident neighbor tasks -- L2 latency was already
// hidden at 55% occupancy, L1 was not.
// ---------------------------------------------------------------------------
__global__ __launch_bounds__(64, 8) void knn_kernel(
    const float* __restrict__ wt,
    const float4* __restrict__ sp, const int* __restrict__ starts,
    float4* __restrict__ feat, const float4* __restrict__ newp, int N)
{
    __shared__ uint2 cc[64];
    const int lane = threadIdx.x & 63;
    const int gwave = blockIdx.x;                 // task id (linear)
    const int bl = gwave / N;                     // b*2 + list
    const int n = gwave - bl * N;
    const int b = bl >> 1, list = bl & 1;
    const int q = b * N + n;

    const float wt0 = __uint_as_float(__builtin_amdgcn_readfirstlane(
                          __float_as_uint(wt[b * 2])));
    const int k0 = (int)(32 * wt0);
    const int kk = list ? (32 - k0) : k0;         // in [8,24]

    const float4 qp = newp[q];                    // broadcast load
    const float qx = __uint_as_float(__builtin_amdgcn_readfirstlane(__float_as_uint(qp.x)));
    const float qy = __uint_as_float(__builtin_amdgcn_readfirstlane(__float_as_uint(qp.y)));
    const float qz = __uint_as_float(__builtin_amdgcn_readfirstlane(__float_as_uint(qp.z)));
    const float qq = qx * qx + qy * qy + qz * qz;

    const int stv = starts[bl * 65 + lane];       // lane j holds starts[j]

    // query bin via one ballot over the constant boundary table
    const float bv = (lane < 63) ? ZB[lane] : 3.0e38f;
    const int qbin = __popcll(__ballot(qz >= bv));    // 0..63

    const float4* L = sp + (size_t)bl * 4096;

    // rank window centered on the query bin's rank midpoint
    const int st = __shfl(stv, qbin);
    const int en = (qbin >= 63) ? N : __shfl(stv, qbin + 1);
    int s0 = ((st + en) >> 1) - WRANKS / 2;
    s0 = s0 < 0 ? 0 : (s0 > N - WRANKS ? N - WRANKS : s0);
    const int e0 = s0 + WRANKS;

    // ---- pass A: 12 static chunks, 3-stage pipeline, keys in VGPRs ----
    const float4* Lb = L + s0 + lane;
    unsigned kv[WCH];
    unsigned mn = 0xFFFFFFFFu;
    {
        float4 A[3], Bv[3];
#pragma unroll
        for (int c = 0; c < 3; ++c) A[c] = Lb[c << 6];
#pragma unroll
        for (int g = 0; g < 4; ++g) {
            if (g < 3) {
#pragma unroll
                for (int c = 0; c < 3; ++c) Bv[c] = Lb[(g * 3 + 3 + c) << 6];
            }
#pragma unroll
            for (int c = 0; c < 3; ++c) {
                const int ch = g * 3 + c;
                const float dt = fmaf(qz, A[c].z, fmaf(qy, A[c].y, qx * A[c].x));
                kv[ch] = __float_as_uint(fmaxf(fmaf(-2.f, dt, A[c].w + qq), 0.f));
                mn = min(mn, kv[ch]);
            }
            if (g < 3) {
#pragma unroll
                for (int c = 0; c < 3; ++c) A[c] = Bv[c];
            }
        }
    }

    // ---- T = m_(kk): single-chain wave bitonic sort of the 64 lane-mins ----
    unsigned x = mn;
#pragma unroll
    for (int k2 = 2; k2 <= 64; k2 <<= 1) {
#pragma unroll
        for (int jj = k2 >> 1; jj; jj >>= 1) {
            const unsigned y = __shfl_xor(x, jj);
            const bool keepmin = (((lane & jj) == 0) == ((lane & k2) == 0));
            x = keepmin ? min(x, y) : (x > y ? x : y);
        }
    }
    const unsigned Tu = (unsigned)__shfl((int)x, kk - 1);
    const float Tf = __uint_as_float(Tu);

    // ---- window compaction from registers: BATCHED ballots (ILP) ----
    int cnt;
    {
        unsigned long long bals[WCH];
#pragma unroll
        for (int ch = 0; ch < WCH; ++ch)
            bals[ch] = __ballot(kv[ch] <= Tu);
        int base = 0;
#pragma unroll
        for (int ch = 0; ch < WCH; ++ch) {
            const unsigned below = __builtin_amdgcn_mbcnt_hi(
                (unsigned)(bals[ch] >> 32),
                __builtin_amdgcn_mbcnt_lo((unsigned)bals[ch], 0u));
            const unsigned idx = (unsigned)base + below;
            if ((kv[ch] <= Tu) && idx < 64u)
                cc[idx] = make_uint2(kv[ch], (unsigned)(s0 + (ch << 6) + lane));
            base += (int)__popcll(bals[ch]);
        }
        cnt = base;
    }

    // ---- outside the window: partial-bin remainders + bin-edge expansion ----
    {
        const int binL = __popcll(__ballot(stv <= s0)) - 1;     // bin of rank s0
        if (s0 > 0) {
            const int bs = __shfl(stv, binL);
            if (bs < s0) cscan(L, bs, s0, qx, qy, qz, qq, Tu, cc, cnt, lane);
            for (int jb = binL - 1; jb >= 0; --jb) {
                const float dz = qz - ZB[jb];
                if (dz * dz * 0.99999f > Tf) break;
                const int bs2 = __shfl(stv, jb);
                const int be2 = __shfl(stv, jb + 1);
                cscan(L, bs2, be2, qx, qy, qz, qq, Tu, cc, cnt, lane);
            }
        }
        if (e0 < N) {
            const int binR = __popcll(__ballot(stv <= e0)) - 1; // bin of rank e0
            const int re = (binR >= 63) ? N : __shfl(stv, binR + 1);
            if (e0 < re) cscan(L, e0, re, qx, qy, qz, qq, Tu, cc, cnt, lane);
            for (int jb = binR + 1; jb <= 63; ++jb) {
                const float dz = ZB[jb - 1] - qz;
                if (dz * dz * 0.99999f > Tf) break;
                const int bs2 = __shfl(stv, jb);
                const int be2 = (jb >= 63) ? N : __shfl(stv, jb + 1);
                cscan(L, bs2, be2, qx, qy, qz, qq, Tu, cc, cnt, lane);
            }
        }
    }

    // ---- finalize: single-chain sort, write top-kk (fallback if overflow) --
    const int obase = (q << 5) + (list ? k0 : 0);
    if (cnt <= 64)
        sort_write(cc, cnt, L, kk, obase, qx, qy, qz, feat, lane);
    else
        fallback_full(L, N, kk, obase, qx, qy, qz, qq, feat, lane);
}

// ---------------------------------------------------------------------------
// K2: per-sample feature moments (S=sum f [4], M=sum f f^T [10]).
// ---------------------------------------------------------------------------
__global__ __launch_bounds__(256) void moment_stats_kernel(
    const float4* __restrict__ feat, float* __restrict__ stats1, int N)
{
    const int t = threadIdx.x, lane = t & 63;
    const int bpb = 64;
    const int b = blockIdx.x / bpb;
    const int ppb = (N * 32) / bpb;
    const size_t base = (size_t)b * N * 32 + (size_t)(blockIdx.x % bpb) * ppb;
    float a[14];
#pragma unroll
    for (int i = 0; i < 14; ++i) a[i] = 0.f;
    for (int i = t; i < ppb; i += 256) {
        const float4 f = feat[base + i];
        a[0] += f.x; a[1] += f.y; a[2] += f.z; a[3] += f.w;
        a[4] = fmaf(f.x, f.x, a[4]);  a[5] = fmaf(f.x, f.y, a[5]);
        a[6] = fmaf(f.x, f.z, a[6]);  a[7] = fmaf(f.x, f.w, a[7]);
        a[8] = fmaf(f.y, f.y, a[8]);  a[9] = fmaf(f.y, f.z, a[9]);
        a[10] = fmaf(f.y, f.w, a[10]); a[11] = fmaf(f.z, f.z, a[11]);
        a[12] = fmaf(f.z, f.w, a[12]); a[13] = fmaf(f.w, f.w, a[13]);
    }
#pragma unroll
    for (int i = 0; i < 14; ++i) {
        float x = a[i];
#pragma unroll
        for (int o = 32; o; o >>= 1) x += __shfl_down(x, o);
        a[i] = x;
    }
    __shared__ float sm[14];
    if (t < 14) sm[t] = 0.f;
    __syncthreads();
    if (lane == 0) {
#pragma unroll
        for (int i = 0; i < 14; ++i) atomicAdd(&sm[i], a[i]);
    }
    __syncthreads();
    if (t < 14) atomicAdd(&stats1[b * 14 + t], sm[t]);
}

// ---------------------------------------------------------------------------
// K3/K4: conv1+gn1+relu -> bf16 h in LDS -> conv2 via MFMA 16x16x32.
// R11: tile 512 -> 256 points/block (h_lds 40 KB -> 20 KB, ~22 KB total)
// so LDS allows up to 7 blocks/CU (was 3) -- occupancy lever for this
// latency-bound serial-loop kernel. Grid doubles to (B*N*32)/256 blocks.
// Epilogue guarded to the block's 8 queries (t < 128).
// ---------------------------------------------------------------------------
template <int MODE>
__global__ __launch_bounds__(256, 4) void conv2_pass_kernel(
    const float4* __restrict__ feat,
    const float* __restrict__ w1, const float* __restrict__ b1,
    const float* __restrict__ gn1w, const float* __restrict__ gn1b,
    const float* __restrict__ stats1,
    const float* __restrict__ w2, const float* __restrict__ b2,
    const float* __restrict__ gn2w, const float* __restrict__ gn2b,
    float* __restrict__ stats2,
    const float4* __restrict__ newp, float* __restrict__ out,
    int N, float inv_cnt)
{
    const int t = threadIdx.x, lane = t & 63, wv = t >> 6;
    const int quad = lane >> 4, col = lane & 15;
    const int bpb = (N * 32) / 256;
    const int b = blockIdx.x / bpb;
    const int pblock = (blockIdx.x - b * bpb) * 256;
    const size_t pbase = (size_t)b * N * 32 + pblock + wv * 64;

    __shared__ float sfin[24];
    __shared__ float sacc[16];
    __shared__ unsigned short h_lds[256 * 40];
    __shared__ float ssc[256];

    if (t < 16) sacc[t] = 0.f;
    if (t < 4) {
        const float cnt = (float)(N * 32);
        const float* mm = stats1 + b * 14;
        const float S0 = mm[0], S1 = mm[1], S2 = mm[2], S3 = mm[3];
        float sum = 0.f, sq = 0.f;
        for (int cch = 0; cch < 8; ++cch) {
            const int cid = t * 8 + cch;
            const float4 w = ((const float4*)w1)[cid];
            const float bb = b1[cid];
            const float ws = w.x * S0 + w.y * S1 + w.z * S2 + w.w * S3;
            const float wMw =
                w.x * w.x * mm[4] + w.y * w.y * mm[8] + w.z * w.z * mm[11] +
                w.w * w.w * mm[13] +
                2.f * (w.x * w.y * mm[5] + w.x * w.z * mm[6] + w.x * w.w * mm[7] +
                       w.y * w.z * mm[9] + w.y * w.w * mm[10] + w.z * w.w * mm[12]);
            sum += cnt * bb + ws;
            sq += cnt * bb * bb + 2.f * bb * ws + wMw;
        }
        const float mu = sum * inv_cnt, var = sq * inv_cnt - mu * mu;
        sfin[2 * t] = mu; sfin[2 * t + 1] = rsqrtf(var + 1e-5f);
    }
    if (MODE == 1 && t >= 4 && t < 12) {
        const int g = t - 4;
        const float S = stats2[b * 16 + g], Q = stats2[b * 16 + 8 + g];
        const float mu = S * inv_cnt, var = Q * inv_cnt - mu * mu;
        sfin[8 + 2 * g] = mu; sfin[8 + 2 * g + 1] = rsqrtf(var + 1e-5f);
    }
    __syncthreads();

    const int c1 = lane & 31, pt = lane >> 5;
    const float4 w1r = ((const float4*)w1)[c1];
    const float b1c = b1[c1];
    const int g1 = c1 >> 3;
    const float sc1 = sfin[2 * g1 + 1] * gn1w[c1];
    const float sh1 = gn1b[c1] - sfin[2 * g1] * sc1;

    for (int it = 0; it < 32; ++it) {
        const size_t p = pbase + it * 2;
        const float4 f = feat[p + pt];
        const float y = b1c + w1r.x * f.x + w1r.y * f.y + w1r.z * f.z + w1r.w * f.w;
        const float h = fmaxf(0.f, fmaf(y, sc1, sh1));
        h_lds[(wv * 64 + it * 2 + pt) * 40 + c1] = f2bf(h);
    }

    s8v afr[4];
#pragma unroll
    for (int T = 0; T < 4; ++T) {
        const int row = T * 16 + col;
#pragma unroll
        for (int j2 = 0; j2 < 8; ++j2)
            afr[T][j2] = (short)f2bf(w2[row * 32 + quad * 8 + j2]);
    }

    float b2v[4][4], sc2v[4][4], sh2v[4][4];
#pragma unroll
    for (int T = 0; T < 4; ++T)
#pragma unroll
        for (int r4 = 0; r4 < 4; ++r4) {
            const int cch = T * 16 + quad * 4 + r4;
            b2v[T][r4] = b2[cch];
            if (MODE == 1) {
                const int g2 = cch >> 3;
                const float sc = sfin[8 + 2 * g2 + 1] * gn2w[cch];
                sc2v[T][r4] = sc;
                sh2v[T][r4] = gn2b[cch] - sfin[8 + 2 * g2] * sc + b2[cch] * sc;
            }
        }

    float gsum[4] = {0, 0, 0, 0}, gsq[4] = {0, 0, 0, 0};

    for (int pt16 = 0; pt16 < 4; ++pt16) {
        const int row = wv * 64 + pt16 * 16 + col;
        const s8v bfr = *(const s8v*)&h_lds[row * 40 + quad * 8];
        f32x4 acc[4];
#pragma unroll
        for (int T = 0; T < 4; ++T) {
            acc[T] = (f32x4){0.f, 0.f, 0.f, 0.f};
            acc[T] = __builtin_amdgcn_mfma_f32_16x16x32_bf16(afr[T], bfr, acc[T], 0, 0, 0);
        }
        if (MODE == 0) {
#pragma unroll
            for (int T = 0; T < 4; ++T)
#pragma unroll
                for (int r4 = 0; r4 < 4; ++r4) {
                    const float v = acc[T][r4] + b2v[T][r4];
                    gsum[T] += v;
                    gsq[T] = fmaf(v, v, gsq[T]);
                }
        } else {
            float s = -3.0e38f;
#pragma unroll
            for (int T = 0; T < 4; ++T)
#pragma unroll
                for (int r4 = 0; r4 < 4; ++r4)
                    s = fmaxf(s, fmaxf(0.f, fmaf(acc[T][r4], sc2v[T][r4], sh2v[T][r4])));
            s = fmaxf(s, __shfl_xor(s, 16));
            s = fmaxf(s, __shfl_xor(s, 32));
            if (quad == 0) ssc[wv * 64 + pt16 * 16 + col] = s;
        }
    }

    if (MODE == 0) {
#pragma unroll
        for (int T = 0; T < 4; ++T) {
#pragma unroll
            for (int o = 1; o < 16; o <<= 1) {
                gsum[T] += __shfl_xor(gsum[T], o);
                gsq[T] += __shfl_xor(gsq[T], o);
            }
            gsum[T] += __shfl_xor(gsum[T], 16);
            gsq[T] += __shfl_xor(gsq[T], 16);
        }
        if (lane == 0) {
#pragma unroll
            for (int T = 0; T < 4; ++T) {
                atomicAdd(&sacc[2 * T], gsum[T]);
                atomicAdd(&sacc[8 + 2 * T], gsq[T]);
            }
        }
        if (lane == 32) {
#pragma unroll
            for (int T = 0; T < 4; ++T) {
                atomicAdd(&sacc[2 * T + 1], gsum[T]);
                atomicAdd(&sacc[8 + 2 * T + 1], gsq[T]);
            }
        }
        __syncthreads();
        if (t < 16) atomicAdd(&stats2[b * 16 + t], sacc[t]);
    } else {
        __syncthreads();
        // 256 points = 8 queries per block; only threads t<128 participate
        const int qi = t >> 4, sub = t & 15;
        if (qi < 8) {
            const int qg = (b * N * 32 + pblock) / 32 + qi;
            const int n = qg - b * N;
            const float s0 = ssc[qi * 32 + sub], s1 = ssc[qi * 32 + 16 + sub];
            float mx = fmaxf(s0, s1);
#pragma unroll
            for (int o = 8; o; o >>= 1) mx = fmaxf(mx, __shfl_xor(mx, o));
            const float e0 = __expf(s0 - mx), e1 = __expf(s1 - mx);
            float ssum = e0 + e1;
#pragma unroll
            for (int o = 8; o; o >>= 1) ssum += __shfl_xor(ssum, o);
            const float4 qc = newp[qg];
            const float4 f0 = feat[(size_t)qg * 32 + sub];
            const float4 f1 = feat[(size_t)qg * 32 + 16 + sub];
            float ax = e0 * (qc.x + f0.x) + e1 * (qc.x + f1.x);
            float ay = e0 * (qc.y + f0.y) + e1 * (qc.y + f1.y);
            float az = e0 * (qc.z + f0.z) + e1 * (qc.z + f1.z);
#pragma unroll
            for (int o = 8; o; o >>= 1) {
                ax += __shfl_xor(ax, o);
                ay += __shfl_xor(ay, o);
                az += __shfl_xor(az, o);
            }
            if (sub == 0) {
                const float inv = 1.f / ssum;
                out[(b * 3 + 0) * N + n] = ax * inv;
                out[(b * 3 + 1) * N + n] = ay * inv;
                out[(b * 3 + 2) * N + n] = az * inv;
            }
        }
    }
}

// ---------------------------------------------------------------------------
extern "C" void kernel_launch(void* const* d_in, const int* in_sizes, int n_in,
                              void* d_out, int out_size, void* d_ws, size_t ws_size,
                              hipStream_t stream)
{
    const float* p0   = (const float*)d_in[0];
    const float* p1   = (const float*)d_in[1];
    const float* wt   = (const float*)d_in[3];
    const int*   perm = (const int*)d_in[4];
    const float* w1   = (const float*)d_in[5];
    const float* b1   = (const float*)d_in[6];
    const float* gn1w = (const float*)d_in[7];
    const float* gn1b = (const float*)d_in[8];
    const float* w2   = (const float*)d_in[9];
    const float* b2   = (const float*)d_in[10];
    const float* gn2w = (const float*)d_in[11];
    const float* gn2b = (const float*)d_in[12];
    float* out = (float*)d_out;

    const int B = in_sizes[3] / 2;
    const int N = in_sizes[0] / (3 * B);

    // workspace layout
    char* ws = (char*)d_ws;
    float4* spts = (float4*)ws;               // B*2*4096 float4 (z-binned CSR)
    size_t off = (size_t)B * 2 * 4096 * sizeof(float4);
    float4* feat = (float4*)(ws + off);       off += (size_t)B * N * 32 * sizeof(float4);
    float4* newp = (float4*)(ws + off);       off += (size_t)B * N * sizeof(float4);
    float* stats1 = (float*)(ws + off);       off += (size_t)B * 14 * sizeof(float);
    float* stats2 = (float*)(ws + off);       off += (size_t)B * 16 * sizeof(float);
    int* starts = (int*)(ws + off);           // B*2*65 CSR offsets

    const float inv_cnt = 1.f / (8.f * (float)N * 32.f);

    // fused prep: zbin (B*2 blocks) + gather (B*N/1024 blocks) + stats zero
    prep_kernel<<<B * 2 + (B * N) / 1024 + 1, 1024, 0, stream>>>(
        p0, p1, wt, perm, spts, starts, newp, stats1, N, B);

    // one wave per (b,list,n) task -> B*2*N single-wave blocks of 64 threads
    knn_kernel<<<B * 2 * N, 64, 0, stream>>>(
        wt, spts, starts, feat, newp, N);

    moment_stats_kernel<<<B * 64, 256, 0, stream>>>(feat, stats1, N);

    conv2_pass_kernel<0><<<(B * N * 32) / 256, 256, 0, stream>>>(
        feat, w1, b1, gn1w, gn1b, stats1, w2, b2, gn2w, gn2b, stats2,
        newp, out, N, inv_cnt);

    conv2_pass_kernel<1><<<(B * N * 32) / 256, 256, 0, stream>>>(
        feat, w1, b1, gn1w, gn1b, stats1, w2, b2, gn2w, gn2b, stats2,
        newp, out, N, inv_cnt);
}

// Round 12
// 291.313 us; speedup vs baseline: 1.0289x; 1.0289x over previous
//
#include <hip/hip_runtime.h>
#include <math.h>

#define RQ 6               // per-lane queue depth (fallback path only)
constexpr int WRANKS = 768; // phase-1 rank window (12 chunks of 64)
constexpr int WCH = 12;

typedef __attribute__((ext_vector_type(8))) short s8v;    // 8 bf16 (4 VGPRs)
typedef __attribute__((ext_vector_type(4))) float f32x4;  // MFMA acc

__device__ inline unsigned short f2bf(float x) {          // RNE f32->bf16
    const unsigned int u = __float_as_uint(x);
    return (unsigned short)((u + 0x7FFFu + ((u >> 16) & 1u)) >> 16);
}

// N(0,1) quantiles at i/64, i=1..63. PERF-ONLY hint; CSR uses exact counts.
__constant__ float ZB[63] = {
    -2.1539f, -1.8627f, -1.6759f, -1.5341f, -1.4178f, -1.3180f, -1.2299f, -1.1503f,
    -1.0775f, -1.0100f, -0.9468f, -0.8871f, -0.8305f, -0.7764f, -0.7245f, -0.6745f,
    -0.6261f, -0.5791f, -0.5334f, -0.4888f, -0.4451f, -0.4023f, -0.3601f, -0.3186f,
    -0.2776f, -0.2372f, -0.1971f, -0.1573f, -0.1178f, -0.0784f, -0.0392f,  0.0000f,
     0.0392f,  0.0784f,  0.1178f,  0.1573f,  0.1971f,  0.2372f,  0.2776f,  0.3186f,
     0.3601f,  0.4023f,  0.4451f,  0.4888f,  0.5334f,  0.5791f,  0.6261f,  0.6745f,
     0.7245f,  0.7764f,  0.8305f,  0.8871f,  0.9468f,  1.0100f,  1.0775f,  1.1503f,
     1.2299f,  1.3180f,  1.4178f,  1.5341f,  1.6759f,  1.8627f,  2.1539f };

// ---------------------------------------------------------------------------
// K0 (fused prep): blocks 0..B*2-1   : z-bin CSR build (one block per list)
//                  blocks B*2..+31   : query gather (1024 queries/block)
//                  last block        : zero stats1/stats2
// Fusion verified in R10 (+~3us vs separate launches; zbin alone fills only
// 16 of 256 CUs, gather overlaps it).
// ---------------------------------------------------------------------------
__global__ __launch_bounds__(1024) void prep_kernel(
    const float* __restrict__ p0, const float* __restrict__ p1,
    const float* __restrict__ wt, const int* __restrict__ perm,
    float4* __restrict__ sp, int* __restrict__ starts,
    float4* __restrict__ newp, float* __restrict__ statsz,
    int N, int B)
{
    const int t = threadIdx.x;
    const int nzb = B * 2;
    if ((int)blockIdx.x < nzb) {
        // ---- zbin branch (identical math to the verified zbin_kernel) ----
        __shared__ int cnt[64], off[64], cur[64];
        const int bl = blockIdx.x;                // b*2 + list
        const int b = bl >> 1, list = bl & 1;
        const float* rb = (list ? p1 : p0) + (size_t)(b * 3) * N;
        if (t < 64) { cnt[t] = 0; cur[t] = 0; }
        __syncthreads();
        int mybin[4]; float mx[4], my[4], mz[4];
        for (int i = 0; i < 4; ++i) {
            const int idx = i * 1024 + t;
            const float z = rb[2 * N + idx];
            mx[i] = rb[idx]; my[i] = rb[N + idx]; mz[i] = z;
            int bin = 0;
#pragma unroll
            for (int s = 32; s; s >>= 1)
                if (bin + s <= 63 && z >= ZB[bin + s - 1]) bin += s;
            mybin[i] = bin;
            atomicAdd(&cnt[bin], 1);
        }
        __syncthreads();
        if (t < 64) {                             // wave 0: exclusive prefix
            const int v = cnt[t];
            int x = v;
#pragma unroll
            for (int o = 1; o < 64; o <<= 1) {
                const int y = __shfl_up(x, o);
                if (t >= o) x += y;
            }
            off[t] = x - v;
            starts[bl * 65 + t] = x - v;
            if (t == 63) starts[bl * 65 + 64] = x;
        }
        __syncthreads();
        for (int i = 0; i < 4; ++i) {
            const int bin = mybin[i];
            const int pos = off[bin] + atomicAdd(&cur[bin], 1);
            sp[(size_t)bl * 4096 + pos] =
                make_float4(mx[i], my[i], mz[i],
                            fmaf(mx[i], mx[i], fmaf(my[i], my[i], mz[i] * mz[i])));
        }
    } else if ((int)blockIdx.x < nzb + (B * N) / 1024) {
        // ---- gather branch ----
        const int q = ((int)blockIdx.x - nzb) * 1024 + t;
        const int b = q / N, n = q - b * N;
        const float wt0 = wt[b * 2];
        const int N0 = (int)(N * wt0);
        int j; const float* src;
        if (n < N0) { j = perm[(b * 2) * N + n];            src = p0; }
        else        { j = perm[(b * 2 + 1) * N + (n - N0)]; src = p1; }
        newp[q] = make_float4(src[(b * 3) * N + j], src[(b * 3 + 1) * N + j],
                              src[(b * 3 + 2) * N + j], 0.f);
    } else {
        // ---- stats zero branch ----
        if (t < B * 30) statsz[t] = 0.f;
    }
}

// ---------------------------------------------------------------------------
// K1 helpers
// ---------------------------------------------------------------------------
__device__ __forceinline__ void cpush(unsigned key, unsigned pos, unsigned Tu,
                                      bool valid, uint2* __restrict__ cc,
                                      int& cnt)
{
    const bool pred = valid && (key <= Tu);
    const unsigned long long bal = __ballot(pred);
    const unsigned below = __builtin_amdgcn_mbcnt_hi(
        (unsigned)(bal >> 32), __builtin_amdgcn_mbcnt_lo((unsigned)bal, 0u));
    const unsigned idx = (unsigned)cnt + below;
    if (pred && idx < 64u) cc[idx] = make_uint2(key, pos);
    cnt += (int)__popcll(bal);
}

__device__ __forceinline__ void cscan(const float4* __restrict__ L,
                                      int bs, int be,
                                      float qx, float qy, float qz, float qq,
                                      unsigned Tu, uint2* __restrict__ cc,
                                      int& cnt, int lane)
{
    for (int p = bs; p < be; p += 64) {
        const int pos = p + lane;
        const float4 pc = L[min(pos, be - 1)];
        const float dt = fmaf(qz, pc.z, fmaf(qy, pc.y, qx * pc.x));
        const float d = fmaxf(fmaf(-2.f, dt, pc.w + qq), 0.f);
        cpush(__float_as_uint(d), (unsigned)pos, Tu, pos < be, cc, cnt);
    }
}

// single-list 64-wide bitonic sort of candidates, write top-kk.
__device__ __forceinline__ void sort_write(
    const uint2* __restrict__ cc, int cnt,
    const float4* __restrict__ L, int kk, int obase,
    float qx, float qy, float qz, float4* __restrict__ feat, int lane)
{
    const uint2 v = cc[lane];
    unsigned vk = (lane < cnt) ? v.x : 0xFFFFFFFFu;
    unsigned vp = (lane < cnt) ? v.y : 0xFFFFFFFFu;
#pragma unroll
    for (int k2 = 2; k2 <= 64; k2 <<= 1) {
#pragma unroll
        for (int jj = k2 >> 1; jj; jj >>= 1) {
            const unsigned yk = __shfl_xor(vk, jj);
            const unsigned yp = __shfl_xor(vp, jj);
            const bool keepmin = (((lane & jj) == 0) == ((lane & k2) == 0));
            const bool lt = (vk < yk) || ((vk == yk) && (vp < yp));
            const bool sely = keepmin ? (!lt) : lt;
            vk = sely ? yk : vk;
            vp = sely ? yp : vp;
        }
    }
    if (lane < kk) {
        const float4 pc = L[vp & 4095u];
        const float rx = pc.x - qx, ry = pc.y - qy, rz = pc.z - qz;
        feat[obase + lane] =
            make_float4(rx, ry, rz, sqrtf(fmaf(rx, rx, fmaf(ry, ry, rz * rz))));
    }
}

// ---- fallback path (cnt>64, astronomically rare): full-list queue scan ----
__device__ __forceinline__ void qpush(unsigned (&kh)[RQ], unsigned (&kl)[RQ],
                                      unsigned key, unsigned pos)
{
    bool cb[RQ];
#pragma unroll
    for (int s = 0; s < RQ; ++s) cb[s] = key < kh[s];
#pragma unroll
    for (int s = RQ - 1; s >= 1; --s) {
        kh[s] = cb[s - 1] ? kh[s - 1] : (cb[s] ? key : kh[s]);
        kl[s] = cb[s - 1] ? kl[s - 1] : (cb[s] ? pos : kl[s]);
    }
    kh[0] = cb[0] ? key : kh[0];
    kl[0] = cb[0] ? pos : kl[0];
}

__device__ __forceinline__ void pop_extract(
    unsigned (&kh)[RQ], unsigned (&kl)[RQ], int kk,
    const float4* __restrict__ L, int obase,
    float qx, float qy, float qz, float4* __restrict__ feat, int lane)
{
    unsigned mwin = 0;
    for (int rr = 0; rr < kk; ++rr) {
        unsigned gg = kh[0];
#pragma unroll
        for (int off = 32; off; off >>= 1) gg = min(gg, __shfl_xor(gg, off));
        const bool tied = (kh[0] == gg);
        unsigned mc;
        const unsigned long long bal = __ballot(tied);
        if (bal & (bal - 1)) {
            mc = tied ? kl[0] : 0xFFFFFFFFu;
#pragma unroll
            for (int off = 32; off; off >>= 1) mc = min(mc, __shfl_xor(mc, off));
        } else {
            mc = __shfl(kl[0], (int)__ffsll((long long)bal) - 1);
        }
        const bool w = tied && (kl[0] == mc);
        if (lane == rr) mwin = mc;
#pragma unroll
        for (int s = 0; s < RQ - 1; ++s) {
            kh[s] = w ? kh[s + 1] : kh[s];
            kl[s] = w ? kl[s + 1] : kl[s];
        }
        kh[RQ - 1] = w ? 0xFFFFFFFFu : kh[RQ - 1];
        kl[RQ - 1] = w ? 0xFFFFFFFFu : kl[RQ - 1];
    }
    if (lane < kk) {
        const float4 pc = L[mwin & 4095u];
        const float rx = pc.x - qx, ry = pc.y - qy, rz = pc.z - qz;
        feat[obase + lane] =
            make_float4(rx, ry, rz, sqrtf(fmaf(rx, rx, fmaf(ry, ry, rz * rz))));
    }
}

__device__ __forceinline__ void fallback_full(
    const float4* __restrict__ L, int Npts, int kk, int obase,
    float qx, float qy, float qz, float qq,
    float4* __restrict__ feat, int lane)
{
    unsigned kh[RQ], kl[RQ];
#pragma unroll
    for (int s = 0; s < RQ; ++s) { kh[s] = 0xFFFFFFFFu; kl[s] = 0xFFFFFFFFu; }
    for (int p = 0; p < Npts; p += 64) {
        const int pos = p + lane;
        const float4 pc = L[min(pos, Npts - 1)];
        const float dt = fmaf(qz, pc.z, fmaf(qy, pc.y, qx * pc.x));
        const float d = fmaxf(fmaf(-2.f, dt, pc.w + qq), 0.f);
        const unsigned key = (pos < Npts) ? __float_as_uint(d) : 0xFFFFFFFFu;
        qpush(kh, kl, key, (unsigned)pos);
    }
    pop_extract(kh, kl, kk, L, obase, qx, qy, qz, feat, lane);
}

// ---------------------------------------------------------------------------
// K1: exact kNN. R12 = R9 exactly (best measured: 127us): one wave per
// (b,list,n) task, LINEAR mapping (R10's XCD swizzle traded L1 for L2 and
// lost 4us -- reverted), 1-wave blocks (wave-granular backfill), batched-
// ballot window compaction, rank window W=768 with 12 static register-
// resident chunks, bitonic T = m_(kk), remainders + bin-edge-dz^2 exact
// expansion, (key,pos) bitonic selection; cnt>64 -> exact fallback.
// ---------------------------------------------------------------------------
__global__ __launch_bounds__(64, 8) void knn_kernel(
    const float* __restrict__ wt,
    const float4* __restrict__ sp, const int* __restrict__ starts,
    float4* __restrict__ feat, const float4* __restrict__ newp, int N)
{
    __shared__ uint2 cc[64];
    const int lane = threadIdx.x & 63;
    const int gwave = blockIdx.x;                 // task id (linear)
    const int bl = gwave / N;                     // b*2 + list
    const int n = gwave - bl * N;
    const int b = bl >> 1, list = bl & 1;
    const int q = b * N + n;

    const float wt0 = __uint_as_float(__builtin_amdgcn_readfirstlane(
                          __float_as_uint(wt[b * 2])));
    const int k0 = (int)(32 * wt0);
    const int kk = list ? (32 - k0) : k0;         // in [8,24]

    const float4 qp = newp[q];                    // broadcast load
    const float qx = __uint_as_float(__builtin_amdgcn_readfirstlane(__float_as_uint(qp.x)));
    const float qy = __uint_as_float(__builtin_amdgcn_readfirstlane(__float_as_uint(qp.y)));
    const float qz = __uint_as_float(__builtin_amdgcn_readfirstlane(__float_as_uint(qp.z)));
    const float qq = qx * qx + qy * qy + qz * qz;

    const int stv = starts[bl * 65 + lane];       // lane j holds starts[j]

    // query bin via one ballot over the constant boundary table
    const float bv = (lane < 63) ? ZB[lane] : 3.0e38f;
    const int qbin = __popcll(__ballot(qz >= bv));    // 0..63

    const float4* L = sp + (size_t)bl * 4096;

    // rank window centered on the query bin's rank midpoint
    const int st = __shfl(stv, qbin);
    const int en = (qbin >= 63) ? N : __shfl(stv, qbin + 1);
    int s0 = ((st + en) >> 1) - WRANKS / 2;
    s0 = s0 < 0 ? 0 : (s0 > N - WRANKS ? N - WRANKS : s0);
    const int e0 = s0 + WRANKS;

    // ---- pass A: 12 static chunks, 3-stage pipeline, keys in VGPRs ----
    const float4* Lb = L + s0 + lane;
    unsigned kv[WCH];
    unsigned mn = 0xFFFFFFFFu;
    {
        float4 A[3], Bv[3];
#pragma unroll
        for (int c = 0; c < 3; ++c) A[c] = Lb[c << 6];
#pragma unroll
        for (int g = 0; g < 4; ++g) {
            if (g < 3) {
#pragma unroll
                for (int c = 0; c < 3; ++c) Bv[c] = Lb[(g * 3 + 3 + c) << 6];
            }
#pragma unroll
            for (int c = 0; c < 3; ++c) {
                const int ch = g * 3 + c;
                const float dt = fmaf(qz, A[c].z, fmaf(qy, A[c].y, qx * A[c].x));
                kv[ch] = __float_as_uint(fmaxf(fmaf(-2.f, dt, A[c].w + qq), 0.f));
                mn = min(mn, kv[ch]);
            }
            if (g < 3) {
#pragma unroll
                for (int c = 0; c < 3; ++c) A[c] = Bv[c];
            }
        }
    }

    // ---- T = m_(kk): single-chain wave bitonic sort of the 64 lane-mins ----
    unsigned x = mn;
#pragma unroll
    for (int k2 = 2; k2 <= 64; k2 <<= 1) {
#pragma unroll
        for (int jj = k2 >> 1; jj; jj >>= 1) {
            const unsigned y = __shfl_xor(x, jj);
            const bool keepmin = (((lane & jj) == 0) == ((lane & k2) == 0));
            x = keepmin ? min(x, y) : (x > y ? x : y);
        }
    }
    const unsigned Tu = (unsigned)__shfl((int)x, kk - 1);
    const float Tf = __uint_as_float(Tu);

    // ---- window compaction from registers: BATCHED ballots (ILP) ----
    int cnt;
    {
        unsigned long long bals[WCH];
#pragma unroll
        for (int ch = 0; ch < WCH; ++ch)
            bals[ch] = __ballot(kv[ch] <= Tu);
        int base = 0;
#pragma unroll
        for (int ch = 0; ch < WCH; ++ch) {
            const unsigned below = __builtin_amdgcn_mbcnt_hi(
                (unsigned)(bals[ch] >> 32),
                __builtin_amdgcn_mbcnt_lo((unsigned)bals[ch], 0u));
            const unsigned idx = (unsigned)base + below;
            if ((kv[ch] <= Tu) && idx < 64u)
                cc[idx] = make_uint2(kv[ch], (unsigned)(s0 + (ch << 6) + lane));
            base += (int)__popcll(bals[ch]);
        }
        cnt = base;
    }

    // ---- outside the window: partial-bin remainders + bin-edge expansion ----
    {
        const int binL = __popcll(__ballot(stv <= s0)) - 1;     // bin of rank s0
        if (s0 > 0) {
            const int bs = __shfl(stv, binL);
            if (bs < s0) cscan(L, bs, s0, qx, qy, qz, qq, Tu, cc, cnt, lane);
            for (int jb = binL - 1; jb >= 0; --jb) {
                const float dz = qz - ZB[jb];
                if (dz * dz * 0.99999f > Tf) break;
                const int bs2 = __shfl(stv, jb);
                const int be2 = __shfl(stv, jb + 1);
                cscan(L, bs2, be2, qx, qy, qz, qq, Tu, cc, cnt, lane);
            }
        }
        if (e0 < N) {
            const int binR = __popcll(__ballot(stv <= e0)) - 1; // bin of rank e0
            const int re = (binR >= 63) ? N : __shfl(stv, binR + 1);
            if (e0 < re) cscan(L, e0, re, qx, qy, qz, qq, Tu, cc, cnt, lane);
            for (int jb = binR + 1; jb <= 63; ++jb) {
                const float dz = ZB[jb - 1] - qz;
                if (dz * dz * 0.99999f > Tf) break;
                const int bs2 = __shfl(stv, jb);
                const int be2 = (jb >= 63) ? N : __shfl(stv, jb + 1);
                cscan(L, bs2, be2, qx, qy, qz, qq, Tu, cc, cnt, lane);
            }
        }
    }

    // ---- finalize: single-chain sort, write top-kk (fallback if overflow) --
    const int obase = (q << 5) + (list ? k0 : 0);
    if (cnt <= 64)
        sort_write(cc, cnt, L, kk, obase, qx, qy, qz, feat, lane);
    else
        fallback_full(L, N, kk, obase, qx, qy, qz, qq, feat, lane);
}

// ---------------------------------------------------------------------------
// K2: per-sample feature moments (S=sum f [4], M=sum f f^T [10]).
// ---------------------------------------------------------------------------
__global__ __launch_bounds__(256) void moment_stats_kernel(
    const float4* __restrict__ feat, float* __restrict__ stats1, int N)
{
    const int t = threadIdx.x, lane = t & 63;
    const int bpb = 64;
    const int b = blockIdx.x / bpb;
    const int ppb = (N * 32) / bpb;
    const size_t base = (size_t)b * N * 32 + (size_t)(blockIdx.x % bpb) * ppb;
    float a[14];
#pragma unroll
    for (int i = 0; i < 14; ++i) a[i] = 0.f;
    for (int i = t; i < ppb; i += 256) {
        const float4 f = feat[base + i];
        a[0] += f.x; a[1] += f.y; a[2] += f.z; a[3] += f.w;
        a[4] = fmaf(f.x, f.x, a[4]);  a[5] = fmaf(f.x, f.y, a[5]);
        a[6] = fmaf(f.x, f.z, a[6]);  a[7] = fmaf(f.x, f.w, a[7]);
        a[8] = fmaf(f.y, f.y, a[8]);  a[9] = fmaf(f.y, f.z, a[9]);
        a[10] = fmaf(f.y, f.w, a[10]); a[11] = fmaf(f.z, f.z, a[11]);
        a[12] = fmaf(f.z, f.w, a[12]); a[13] = fmaf(f.w, f.w, a[13]);
    }
#pragma unroll
    for (int i = 0; i < 14; ++i) {
        float x = a[i];
#pragma unroll
        for (int o = 32; o; o >>= 1) x += __shfl_down(x, o);
        a[i] = x;
    }
    __shared__ float sm[14];
    if (t < 14) sm[t] = 0.f;
    __syncthreads();
    if (lane == 0) {
#pragma unroll
        for (int i = 0; i < 14; ++i) atomicAdd(&sm[i], a[i]);
    }
    __syncthreads();
    if (t < 14) atomicAdd(&stats1[b * 14 + t], sm[t]);
}

// ---------------------------------------------------------------------------
// K3/K4: conv1+gn1+relu -> bf16 h in LDS -> conv2 via MFMA 16x16x32.
// R12: back to the 512-point tile (R9 exact) -- the 256-tile experiment
// (R11) cost ~7-9us: per-block fixed costs (sfin stats, weight loads,
// stats2 atomics) doubled while occupancy was not conv's limiter.
// ---------------------------------------------------------------------------
template <int MODE>
__global__ __launch_bounds__(256) void conv2_pass_kernel(
    const float4* __restrict__ feat,
    const float* __restrict__ w1, const float* __restrict__ b1,
    const float* __restrict__ gn1w, const float* __restrict__ gn1b,
    const float* __restrict__ stats1,
    const float* __restrict__ w2, const float* __restrict__ b2,
    const float* __restrict__ gn2w, const float* __restrict__ gn2b,
    float* __restrict__ stats2,
    const float4* __restrict__ newp, float* __restrict__ out,
    int N, float inv_cnt)
{
    const int t = threadIdx.x, lane = t & 63, wv = t >> 6;
    const int quad = lane >> 4, col = lane & 15;
    const int bpb = (N * 32) / 512;
    const int b = blockIdx.x / bpb;
    const int pblock = (blockIdx.x - b * bpb) * 512;
    const size_t pbase = (size_t)b * N * 32 + pblock + wv * 128;

    __shared__ float sfin[24];
    __shared__ float sacc[16];
    __shared__ unsigned short h_lds[512 * 40];
    __shared__ float ssc[512];

    if (t < 16) sacc[t] = 0.f;
    if (t < 4) {
        const float cnt = (float)(N * 32);
        const float* mm = stats1 + b * 14;
        const float S0 = mm[0], S1 = mm[1], S2 = mm[2], S3 = mm[3];
        float sum = 0.f, sq = 0.f;
        for (int cch = 0; cch < 8; ++cch) {
            const int cid = t * 8 + cch;
            const float4 w = ((const float4*)w1)[cid];
            const float bb = b1[cid];
            const float ws = w.x * S0 + w.y * S1 + w.z * S2 + w.w * S3;
            const float wMw =
                w.x * w.x * mm[4] + w.y * w.y * mm[8] + w.z * w.z * mm[11] +
                w.w * w.w * mm[13] +
                2.f * (w.x * w.y * mm[5] + w.x * w.z * mm[6] + w.x * w.w * mm[7] +
                       w.y * w.z * mm[9] + w.y * w.w * mm[10] + w.z * w.w * mm[12]);
            sum += cnt * bb + ws;
            sq += cnt * bb * bb + 2.f * bb * ws + wMw;
        }
        const float mu = sum * inv_cnt, var = sq * inv_cnt - mu * mu;
        sfin[2 * t] = mu; sfin[2 * t + 1] = rsqrtf(var + 1e-5f);
    }
    if (MODE == 1 && t >= 4 && t < 12) {
        const int g = t - 4;
        const float S = stats2[b * 16 + g], Q = stats2[b * 16 + 8 + g];
        const float mu = S * inv_cnt, var = Q * inv_cnt - mu * mu;
        sfin[8 + 2 * g] = mu; sfin[8 + 2 * g + 1] = rsqrtf(var + 1e-5f);
    }
    __syncthreads();

    const int c1 = lane & 31, pt = lane >> 5;
    const float4 w1r = ((const float4*)w1)[c1];
    const float b1c = b1[c1];
    const int g1 = c1 >> 3;
    const float sc1 = sfin[2 * g1 + 1] * gn1w[c1];
    const float sh1 = gn1b[c1] - sfin[2 * g1] * sc1;

    for (int it = 0; it < 64; ++it) {
        const size_t p = pbase + it * 2;
        const float4 f = feat[p + pt];
        const float y = b1c + w1r.x * f.x + w1r.y * f.y + w1r.z * f.z + w1r.w * f.w;
        const float h = fmaxf(0.f, fmaf(y, sc1, sh1));
        h_lds[(wv * 128 + it * 2 + pt) * 40 + c1] = f2bf(h);
    }

    s8v afr[4];
#pragma unroll
    for (int T = 0; T < 4; ++T) {
        const int row = T * 16 + col;
#pragma unroll
        for (int j2 = 0; j2 < 8; ++j2)
            afr[T][j2] = (short)f2bf(w2[row * 32 + quad * 8 + j2]);
    }

    float b2v[4][4], sc2v[4][4], sh2v[4][4];
#pragma unroll
    for (int T = 0; T < 4; ++T)
#pragma unroll
        for (int r4 = 0; r4 < 4; ++r4) {
            const int cch = T * 16 + quad * 4 + r4;
            b2v[T][r4] = b2[cch];
            if (MODE == 1) {
                const int g2 = cch >> 3;
                const float sc = sfin[8 + 2 * g2 + 1] * gn2w[cch];
                sc2v[T][r4] = sc;
                sh2v[T][r4] = gn2b[cch] - sfin[8 + 2 * g2] * sc + b2[cch] * sc;
            }
        }

    float gsum[4] = {0, 0, 0, 0}, gsq[4] = {0, 0, 0, 0};

    for (int pt16 = 0; pt16 < 8; ++pt16) {
        const int row = wv * 128 + pt16 * 16 + col;
        const s8v bfr = *(const s8v*)&h_lds[row * 40 + quad * 8];
        f32x4 acc[4];
#pragma unroll
        for (int T = 0; T < 4; ++T) {
            acc[T] = (f32x4){0.f, 0.f, 0.f, 0.f};
            acc[T] = __builtin_amdgcn_mfma_f32_16x16x32_bf16(afr[T], bfr, acc[T], 0, 0, 0);
        }
        if (MODE == 0) {
#pragma unroll
            for (int T = 0; T < 4; ++T)
#pragma unroll
                for (int r4 = 0; r4 < 4; ++r4) {
                    const float v = acc[T][r4] + b2v[T][r4];
                    gsum[T] += v;
                    gsq[T] = fmaf(v, v, gsq[T]);
                }
        } else {
            float s = -3.0e38f;
#pragma unroll
            for (int T = 0; T < 4; ++T)
#pragma unroll
                for (int r4 = 0; r4 < 4; ++r4)
                    s = fmaxf(s, fmaxf(0.f, fmaf(acc[T][r4], sc2v[T][r4], sh2v[T][r4])));
            s = fmaxf(s, __shfl_xor(s, 16));
            s = fmaxf(s, __shfl_xor(s, 32));
            if (quad == 0) ssc[wv * 128 + pt16 * 16 + col] = s;
        }
    }

    if (MODE == 0) {
#pragma unroll
        for (int T = 0; T < 4; ++T) {
#pragma unroll
            for (int o = 1; o < 16; o <<= 1) {
                gsum[T] += __shfl_xor(gsum[T], o);
                gsq[T] += __shfl_xor(gsq[T], o);
            }
            gsum[T] += __shfl_xor(gsum[T], 16);
            gsq[T] += __shfl_xor(gsq[T], 16);
        }
        if (lane == 0) {
#pragma unroll
            for (int T = 0; T < 4; ++T) {
                atomicAdd(&sacc[2 * T], gsum[T]);
                atomicAdd(&sacc[8 + 2 * T], gsq[T]);
            }
        }
        if (lane == 32) {
#pragma unroll
            for (int T = 0; T < 4; ++T) {
                atomicAdd(&sacc[2 * T + 1], gsum[T]);
                atomicAdd(&sacc[8 + 2 * T + 1], gsq[T]);
            }
        }
        __syncthreads();
        if (t < 16) atomicAdd(&stats2[b * 16 + t], sacc[t]);
    } else {
        __syncthreads();
        const int qi = t >> 4, sub = t & 15;
        const int qg = (b * N * 32 + pblock) / 32 + qi;
        const int n = qg - b * N;
        const float s0 = ssc[qi * 32 + sub], s1 = ssc[qi * 32 + 16 + sub];
        float mx = fmaxf(s0, s1);
#pragma unroll
        for (int o = 8; o; o >>= 1) mx = fmaxf(mx, __shfl_xor(mx, o));
        const float e0 = __expf(s0 - mx), e1 = __expf(s1 - mx);
        float ssum = e0 + e1;
#pragma unroll
        for (int o = 8; o; o >>= 1) ssum += __shfl_xor(ssum, o);
        const float4 qc = newp[qg];
        const float4 f0 = feat[(size_t)qg * 32 + sub];
        const float4 f1 = feat[(size_t)qg * 32 + 16 + sub];
        float ax = e0 * (qc.x + f0.x) + e1 * (qc.x + f1.x);
        float ay = e0 * (qc.y + f0.y) + e1 * (qc.y + f1.y);
        float az = e0 * (qc.z + f0.z) + e1 * (qc.z + f1.z);
#pragma unroll
        for (int o = 8; o; o >>= 1) {
            ax += __shfl_xor(ax, o);
            ay += __shfl_xor(ay, o);
            az += __shfl_xor(az, o);
        }
        if (sub == 0) {
            const float inv = 1.f / ssum;
            out[(b * 3 + 0) * N + n] = ax * inv;
            out[(b * 3 + 1) * N + n] = ay * inv;
            out[(b * 3 + 2) * N + n] = az * inv;
        }
    }
}

// ---------------------------------------------------------------------------
extern "C" void kernel_launch(void* const* d_in, const int* in_sizes, int n_in,
                              void* d_out, int out_size, void* d_ws, size_t ws_size,
                              hipStream_t stream)
{
    const float* p0   = (const float*)d_in[0];
    const float* p1   = (const float*)d_in[1];
    const float* wt   = (const float*)d_in[3];
    const int*   perm = (const int*)d_in[4];
    const float* w1   = (const float*)d_in[5];
    const float* b1   = (const float*)d_in[6];
    const float* gn1w = (const float*)d_in[7];
    const float* gn1b = (const float*)d_in[8];
    const float* w2   = (const float*)d_in[9];
    const float* b2   = (const float*)d_in[10];
    const float* gn2w = (const float*)d_in[11];
    const float* gn2b = (const float*)d_in[12];
    float* out = (float*)d_out;

    const int B = in_sizes[3] / 2;
    const int N = in_sizes[0] / (3 * B);

    // workspace layout
    char* ws = (char*)d_ws;
    float4* spts = (float4*)ws;               // B*2*4096 float4 (z-binned CSR)
    size_t off = (size_t)B * 2 * 4096 * sizeof(float4);
    float4* feat = (float4*)(ws + off);       off += (size_t)B * N * 32 * sizeof(float4);
    float4* newp = (float4*)(ws + off);       off += (size_t)B * N * sizeof(float4);
    float* stats1 = (float*)(ws + off);       off += (size_t)B * 14 * sizeof(float);
    float* stats2 = (float*)(ws + off);       off += (size_t)B * 16 * sizeof(float);
    int* starts = (int*)(ws + off);           // B*2*65 CSR offsets

    const float inv_cnt = 1.f / (8.f * (float)N * 32.f);

    // fused prep: zbin (B*2 blocks) + gather (B*N/1024 blocks) + stats zero
    prep_kernel<<<B * 2 + (B * N) / 1024 + 1, 1024, 0, stream>>>(
        p0, p1, wt, perm, spts, starts, newp, stats1, N, B);

    // one wave per (b,list,n) task -> B*2*N single-wave blocks of 64 threads
    knn_kernel<<<B * 2 * N, 64, 0, stream>>>(
        wt, spts, starts, feat, newp, N);

    moment_stats_kernel<<<B * 64, 256, 0, stream>>>(feat, stats1, N);

    conv2_pass_kernel<0><<<(B * N * 32) / 512, 256, 0, stream>>>(
        feat, w1, b1, gn1w, gn1b, stats1, w2, b2, gn2w, gn2b, stats2,
        newp, out, N, inv_cnt);

    conv2_pass_kernel<1><<<(B * N * 32) / 512, 256, 0, stream>>>(
        feat, w1, b1, gn1w, gn1b, stats1, w2, b2, gn2w, gn2b, stats2,
        newp, out, N, inv_cnt);
}